// Round 6
// baseline (125.519 us; speedup 1.0000x reference)
//
#include <hip/hip_runtime.h>
#include <math.h>

// B=8, PN=8 -> BP=64; PL=511 -> L=512; NV=2; H=8; DK=DV=32; D=256; DM=512; HID=1024.
namespace {
constexpr int L   = 512;
constexpr int D   = 256;
constexpr int DM  = 512;
constexpr int HID = 1024;
constexpr float INV_SQRT_DK = 0.17677669529663687f;  // 1/sqrt(32)

// thetas[j] = 1000^(-j/16), precomputed literals
__device__ __constant__ float THETA[16] = {
  1.0f,           0.64938163f,  0.42169650f,  0.27384196f,
  0.17782794f,    0.11547820f,  0.074989421f, 0.048696753f,
  0.031622777f,   0.020535250f, 0.013335214f, 0.0086596432f,
  0.0056234133f,  0.0036517412f,0.0023713737f,0.0015399265f };

// ---------------- K1: attention, one block per (bp, head) ----------------
__global__ __launch_bounds__(512, 2)
void k_attn(const float* __restrict__ x, const float* __restrict__ t,
            const int* __restrict__ mask, const float* __restrict__ emb,
            const float* __restrict__ Wq, const float* __restrict__ Wk,
            const float* __restrict__ Wv, float* __restrict__ last,
            int* __restrict__ counters) {
  const int bp = blockIdx.x & 63, h = blockIdx.x >> 6;
  const int tid = threadIdx.x, lane = tid & 63, wid = tid >> 6;

  // zero the fused-kernel counters for this call (visible at kernel boundary)
  if (blockIdx.x == 0 && tid < 16) counters[tid] = 0;

  __shared__ float xx0s[L], xx1s[L];
  __shared__ float wq0[32], wq1[32], wk0[32], wk1[32], wv0[32], wv1[32];
  __shared__ float qh[32];
  __shared__ float red[24];
  __shared__ int   m0s;

  if (tid == 0) { xx0s[0] = emb[0]; xx1s[0] = emb[1]; m0s = mask[bp * L]; }
  else {
    float2 v = reinterpret_cast<const float2*>(x)[bp * (L - 1) + tid - 1];
    xx0s[tid] = v.x; xx1s[tid] = v.y;
  }
  if (tid < 32) {
    wq0[tid] = Wq[h * 32 + tid];       wq1[tid] = Wq[256 + h * 32 + tid];
    wk0[tid] = Wk[h * 32 + tid];       wk1[tid] = Wk[256 + h * 32 + tid];
    wv0[tid] = Wv[h * 32 + tid];       wv1[tid] = Wv[256 + h * 32 + tid];
  }

  const float tl = t[bp * L + tid];
  const int   ml = mask[bp * L + tid];
  float cj[16], sj[16];
  #pragma unroll
  for (int j = 0; j < 16; ++j) __sincosf(tl * THETA[j], &sj[j], &cj[j]);
  __syncthreads();

  if (tid < 16) {  // query row (pos 0), RoPE'd + pre-scaled
    const float t0 = t[bp * L];
    const float re = xx0s[0] * wq0[2 * tid]     + xx1s[0] * wq1[2 * tid];
    const float im = xx0s[0] * wq0[2 * tid + 1] + xx1s[0] * wq1[2 * tid + 1];
    float s0, c0;
    __sincosf(t0 * THETA[tid], &s0, &c0);
    qh[2 * tid]     = (re * c0 - im * s0) * INV_SQRT_DK;
    qh[2 * tid + 1] = (re * s0 + im * c0) * INV_SQRT_DK;
  }
  __syncthreads();

  const float xl0 = xx0s[tid], xl1 = xx1s[tid];
  float sc = 0.f;
  #pragma unroll
  for (int j = 0; j < 16; ++j) {
    const int c = 2 * j;
    const float xr  = xl0 * wk0[c]     + xl1 * wk1[c];
    const float xi  = xl0 * wk0[c + 1] + xl1 * wk1[c + 1];
    const float kre = xr * cj[j] - xi * sj[j];
    const float kim = xr * sj[j] + xi * cj[j];
    sc += qh[c] * kre + qh[c + 1] * kim;
  }
  if ((m0s * ml) == 0) sc = -1e9f;

  float mx = sc;
  #pragma unroll
  for (int o = 32; o; o >>= 1) mx = fmaxf(mx, __shfl_xor(mx, o));
  if (lane == 0) red[wid] = mx;
  __syncthreads();
  mx = red[0];
  #pragma unroll
  for (int w = 1; w < 8; ++w) mx = fmaxf(mx, red[w]);

  const float e = __expf(sc - mx);
  float se = e, s0a = e * xl0, s1a = e * xl1;
  #pragma unroll
  for (int o = 32; o; o >>= 1) {
    se  += __shfl_xor(se, o);
    s0a += __shfl_xor(s0a, o);
    s1a += __shfl_xor(s1a, o);
  }
  __syncthreads();
  if (lane == 0) { red[wid] = se; red[8 + wid] = s0a; red[16 + wid] = s1a; }
  __syncthreads();
  se = 0.f; s0a = 0.f; s1a = 0.f;
  #pragma unroll
  for (int w = 0; w < 8; ++w) { se += red[w]; s0a += red[8 + w]; s1a += red[16 + w]; }

  // attn@V == ((attn@xx)@Wv): NV=2, V carries no RoPE
  if (tid < 32) last[bp * 256 + h * 32 + tid] = (s0a * wv0[tid] + s1a * wv1[tid]) / se;
}

// ---------------- K2: fused FFN + tail ----------------
// Grid 512 x 512 threads, exactly 2 blocks/CU -> all co-resident.
// bids 0..255: producers (kt = bid&15, mt = bid>>4), as proven in round 5.
// bids 256..511: tail blocks (bp, ct); spin on cnt[bp>>2]==16, then
// partial-reduce + residual + LN + out tile (proven k_tail math).
__global__ __launch_bounds__(512, 2)
void k_fused(const float* __restrict__ last, const float* __restrict__ W1,
             const float* __restrict__ b1, const float* __restrict__ W2,
             const float* __restrict__ b2, const float* __restrict__ ln_g,
             const float* __restrict__ ln_b, const float* __restrict__ Wo,
             float* __restrict__ partial, int* __restrict__ counters,
             float* __restrict__ out) {
  const int tid = threadIdx.x, lane = tid & 63, wid = tid >> 6;

  __shared__ float ls[4][256];
  __shared__ float s_part[2][4][64];
  __shared__ float hs[4][64];
  __shared__ float s_y[2][256];
  __shared__ float s_yn[256];
  __shared__ float s_op[8][128];
  __shared__ float red[8];

  if (blockIdx.x < 256) {
    // ================= producer =================
    const int kt = blockIdx.x & 15, mt = blockIdx.x >> 4;
    const int wave = tid >> 6, r = wave & 3, kh = wave >> 2;

    #pragma unroll
    for (int q = 0; q < 2; ++q) {
      const int idx = tid + q * 512;
      ls[idx >> 8][idx & 255] = last[(mt * 4 + (idx >> 8)) * 256 + (idx & 255)];
    }
    __syncthreads();

    // W1 phase: col j = kt*64+lane, K-half kh, 4 interleaved acc chains
    const int j = kt * 64 + lane;
    {
      const float* w1p = W1 + (size_t)(kh * 128) * HID + j;
      const float* lp  = &ls[r][kh * 128];
      float a0 = 0.f, a1 = 0.f, a2 = 0.f, a3 = 0.f;
      #pragma unroll 8
      for (int ii = 0; ii < 32; ++ii) {
        const float w_0 = w1p[(4 * ii + 0) * HID];
        const float w_1 = w1p[(4 * ii + 1) * HID];
        const float w_2 = w1p[(4 * ii + 2) * HID];
        const float w_3 = w1p[(4 * ii + 3) * HID];
        a0 = fmaf(lp[4 * ii + 0], w_0, a0);
        a1 = fmaf(lp[4 * ii + 1], w_1, a1);
        a2 = fmaf(lp[4 * ii + 2], w_2, a2);
        a3 = fmaf(lp[4 * ii + 3], w_3, a3);
      }
      s_part[kh][r][lane] = (a0 + a1) + (a2 + a3);
    }
    __syncthreads();
    if (kh == 0)
      hs[r][lane] = fmaxf(s_part[0][r][lane] + s_part[1][r][lane] + b1[j], 0.f);
    __syncthreads();

    // W2 phase: row r, cols kh*128 + 2*lane (+1); float2 loads, 2 chains
    {
      const int c0 = kh * 128 + 2 * lane;
      const float* w2p = W2 + (size_t)(kt * 64) * D + c0;
      float f0 = 0.f, f1 = 0.f;
      #pragma unroll 16
      for (int k = 0; k < 64; ++k) {
        const float2 w = *reinterpret_cast<const float2*>(w2p + (size_t)k * D);
        const float hv = hs[r][k];
        f0 = fmaf(hv, w.x, f0);
        f1 = fmaf(hv, w.y, f1);
      }
      float2 o = make_float2(f0, f1);
      *reinterpret_cast<float2*>(&partial[(size_t)(kt * 64 + mt * 4 + r) * 256 + c0]) = o;
    }

    // release: make partials agent-visible, then signal
    __threadfence();
    __syncthreads();
    if (tid == 0) atomicAdd(&counters[mt], 1);
  } else {
    // ================= tail =================
    const int b2id = blockIdx.x - 256;
    const int bp = b2id >> 2, ct = b2id & 3, mt = bp >> 2;

    if (tid == 0) {
      while (__hip_atomic_load(&counters[mt], __ATOMIC_ACQUIRE,
                               __HIP_MEMORY_SCOPE_AGENT) < 16) {
        __builtin_amdgcn_s_sleep(2);
      }
    }
    __syncthreads();
    __threadfence();  // acquire: invalidate stale cached partials

    // Phase A: partial reduce, 2-way split over kt
    {
      const int col = tid & 255, khh = tid >> 8;
      float acc = khh ? 0.f : (last[bp * 256 + col] + b2[col]);
      #pragma unroll
      for (int kt = khh * 8; kt < khh * 8 + 8; ++kt)
        acc += partial[(size_t)(kt * 64 + bp) * 256 + col];
      s_y[khh][col] = acc;
    }
    __syncthreads();

    // Phase B: layernorm over 256
    float y = 0.f;
    if (tid < 256) y = s_y[0][tid] + s_y[1][tid];
    float ssum = (tid < 256) ? y : 0.f, ssq = (tid < 256) ? y * y : 0.f;
    #pragma unroll
    for (int o = 32; o; o >>= 1) { ssum += __shfl_xor(ssum, o); ssq += __shfl_xor(ssq, o); }
    if (tid < 256 && lane == 0) { red[wid] = ssum; red[4 + wid] = ssq; }
    __syncthreads();
    ssum = red[0] + red[1] + red[2] + red[3];
    ssq  = red[4] + red[5] + red[6] + red[7];
    const float mu   = ssum / 256.f;
    const float var  = ssq / 256.f - mu * mu;
    const float rstd = rsqrtf(var + 1e-5f);
    if (tid < 256) s_yn[tid] = (y - mu) * rstd * ln_g[tid] + ln_b[tid];
    __syncthreads();

    // Phase C: out tile (128 cols), float2 Wo loads, 8-way K-split
    {
      const int l6 = tid & 63, kq = tid >> 6;
      const int c0 = ct * 128 + 2 * l6;
      float f0 = 0.f, f1 = 0.f;
      #pragma unroll 8
      for (int i = kq * 32; i < kq * 32 + 32; ++i) {
        const float2 w = *reinterpret_cast<const float2*>(&Wo[(size_t)i * DM + c0]);
        const float yv = s_yn[i];
        f0 = fmaf(yv, w.x, f0);
        f1 = fmaf(yv, w.y, f1);
      }
      s_op[kq][2 * l6] = f0; s_op[kq][2 * l6 + 1] = f1;
    }
    __syncthreads();
    if (tid < 128) {
      float a = 0.f;
      #pragma unroll
      for (int kq = 0; kq < 8; ++kq) a += s_op[kq][tid];
      out[(size_t)bp * DM + ct * 128 + tid] = a;
    }
  }
}
}  // namespace

extern "C" void kernel_launch(void* const* d_in, const int* in_sizes, int n_in,
                              void* d_out, int out_size, void* d_ws, size_t ws_size,
                              hipStream_t stream) {
  const float* x    = (const float*)d_in[0];
  const float* t    = (const float*)d_in[1];
  const int*   mask = (const int*)  d_in[2];
  const float* emb  = (const float*)d_in[3];
  const float* Wq   = (const float*)d_in[4];
  const float* Wk   = (const float*)d_in[5];
  const float* Wv   = (const float*)d_in[6];
  const float* Wo   = (const float*)d_in[7];
  const float* lng  = (const float*)d_in[8];
  const float* lnb  = (const float*)d_in[9];
  const float* W1   = (const float*)d_in[10];
  const float* b1   = (const float*)d_in[11];
  const float* W2   = (const float*)d_in[12];
  const float* b2   = (const float*)d_in[13];
  float* out = (float*)d_out;

  float* ws      = (float*)d_ws;
  float* last    = ws;                      // 64*256 floats
  float* partial = ws + 16384;              // 16*64*256 floats
  int*   cnt     = (int*)(ws + 16384 + 262144);  // 16 ints

  k_attn <<<512, 512, 0, stream>>>(x, t, mask, emb, Wq, Wk, Wv, last, cnt);
  k_fused<<<512, 512, 0, stream>>>(last, W1, b1, W2, b2, lng, lnb, Wo,
                                   partial, cnt, out);
}

// Round 7
// 23.451 us; speedup vs baseline: 5.3523x; 5.3523x over previous
//
#include <hip/hip_runtime.h>
#include <math.h>

// B=8, PN=8 -> BP=64; PL=511 -> L=512; NV=2; H=8; DK=DV=32; D=256; DM=512; HID=1024.
namespace {
constexpr int L   = 512;
constexpr int D   = 256;
constexpr int DM  = 512;
constexpr int HID = 1024;
constexpr float INV_SQRT_DK = 0.17677669529663687f;  // 1/sqrt(32)

// thetas[j] = 1000^(-j/16), precomputed literals
__device__ __constant__ float THETA[16] = {
  1.0f,           0.64938163f,  0.42169650f,  0.27384196f,
  0.17782794f,    0.11547820f,  0.074989421f, 0.048696753f,
  0.031622777f,   0.020535250f, 0.013335214f, 0.0086596432f,
  0.0056234133f,  0.0036517412f,0.0023713737f,0.0015399265f };

// ---------------- K1: attention, one block per (bp, head) ----------------
// No max pass: scores bounded (|sc| ~ <15, fp32-exp safe). All-masked rows
// (mask[bp,0]==0) reproduce the reference's uniform softmax via e=1.
__global__ __launch_bounds__(512, 2)
void k_attn(const float* __restrict__ x, const float* __restrict__ t,
            const int* __restrict__ mask, const float* __restrict__ emb,
            const float* __restrict__ Wq, const float* __restrict__ Wk,
            const float* __restrict__ Wv, float* __restrict__ last) {
  const int bp = blockIdx.x & 63, h = blockIdx.x >> 6;
  const int tid = threadIdx.x, lane = tid & 63, wid = tid >> 6;

  __shared__ float wk0[32], wk1[32], wv0[32], wv1[32];
  __shared__ float red[24];

  if (tid < 32) {
    wk0[tid] = Wk[h * 32 + tid]; wk1[tid] = Wk[256 + h * 32 + tid];
    wv0[tid] = Wv[h * 32 + tid]; wv1[tid] = Wv[256 + h * 32 + tid];
  }

  const int   m0 = mask[bp * L];          // same address all threads (scalar)
  const float tl = t[bp * L + tid];
  const int   ml = mask[bp * L + tid];
  float xl0, xl1;
  if (tid == 0) { xl0 = emb[0]; xl1 = emb[1]; }
  else {
    float2 v = reinterpret_cast<const float2*>(x)[bp * (L - 1) + tid - 1];
    xl0 = v.x; xl1 = v.y;
  }

  float cj[16], sj[16];
  #pragma unroll
  for (int j = 0; j < 16; ++j) __sincosf(tl * THETA[j], &sj[j], &cj[j]);

  // q fragment: lanes 0..15 of every wave hold (qre_j, qim_j), j = lane
  float qre = 0.f, qim = 0.f;
  if (lane < 16) {
    const float t0v = t[bp * L];
    const float e0 = emb[0], e1 = emb[1];
    const float re = e0 * Wq[h * 32 + 2 * lane]     + e1 * Wq[256 + h * 32 + 2 * lane];
    const float im = e0 * Wq[h * 32 + 2 * lane + 1] + e1 * Wq[256 + h * 32 + 2 * lane + 1];
    float s0, c0;
    __sincosf(t0v * THETA[lane], &s0, &c0);
    qre = (re * c0 - im * s0) * INV_SQRT_DK;
    qim = (re * s0 + im * c0) * INV_SQRT_DK;
  }
  __syncthreads();  // wk/wv staged

  float sc = 0.f;
  #pragma unroll
  for (int j = 0; j < 16; ++j) {
    const int c = 2 * j;
    const float xr  = xl0 * wk0[c]     + xl1 * wk1[c];
    const float xi  = xl0 * wk0[c + 1] + xl1 * wk1[c + 1];
    const float kre = xr * cj[j] - xi * sj[j];
    const float kim = xr * sj[j] + xi * cj[j];
    sc += __shfl(qre, j) * kre + __shfl(qim, j) * kim;
  }

  // masked softmax weight (unnormalized); m0==0 -> all masked -> uniform
  const float e = (m0 == 0) ? 1.f : (ml ? __expf(sc) : 0.f);

  // single fused triple reduction: sum(e), sum(e*x0), sum(e*x1)
  float se = e, s0a = e * xl0, s1a = e * xl1;
  #pragma unroll
  for (int o = 32; o; o >>= 1) {
    se  += __shfl_xor(se, o);
    s0a += __shfl_xor(s0a, o);
    s1a += __shfl_xor(s1a, o);
  }
  if (lane == 0) { red[wid] = se; red[8 + wid] = s0a; red[16 + wid] = s1a; }
  __syncthreads();
  se = 0.f; s0a = 0.f; s1a = 0.f;
  #pragma unroll
  for (int w = 0; w < 8; ++w) { se += red[w]; s0a += red[8 + w]; s1a += red[16 + w]; }

  // attn@V == ((attn@xx)@Wv): NV=2, V carries no RoPE
  if (tid < 32) last[bp * 256 + h * 32 + tid] = (s0a * wv0[tid] + s1a * wv1[tid]) / se;
}

// ---------------- K2: fused FFN1+FFN2 K-partial ----------------
// grid 256 = 1 block/CU: kt = bid&15 (same-kt on same XCD), mt = bid>>4.
// 512 threads = 8 waves: r = wave&3 (bp row), kh = wave>>2 (K-half).
__global__ __launch_bounds__(512, 1)
void k_ffn(const float* __restrict__ last, const float* __restrict__ W1,
           const float* __restrict__ b1, const float* __restrict__ W2,
           float* __restrict__ partial) {
  const int kt = blockIdx.x & 15, mt = blockIdx.x >> 4;
  const int tid = threadIdx.x, lane = tid & 63;
  const int wave = tid >> 6, r = wave & 3, kh = wave >> 2;

  __shared__ float ls[4][256];
  __shared__ float s_part[2][4][64];
  __shared__ float hs[4][64];

  #pragma unroll
  for (int q = 0; q < 2; ++q) {
    const int idx = tid + q * 512;
    ls[idx >> 8][idx & 255] = last[(mt * 4 + (idx >> 8)) * 256 + (idx & 255)];
  }
  __syncthreads();

  // W1 phase: col j = kt*64+lane, K-half kh, 4 chains, deep unroll
  const int j = kt * 64 + lane;
  {
    const float* w1p = W1 + (size_t)(kh * 128) * HID + j;
    const float* lp  = &ls[r][kh * 128];
    float a0 = 0.f, a1 = 0.f, a2 = 0.f, a3 = 0.f;
    #pragma unroll 16
    for (int ii = 0; ii < 32; ++ii) {
      const float w_0 = w1p[(4 * ii + 0) * HID];
      const float w_1 = w1p[(4 * ii + 1) * HID];
      const float w_2 = w1p[(4 * ii + 2) * HID];
      const float w_3 = w1p[(4 * ii + 3) * HID];
      a0 = fmaf(lp[4 * ii + 0], w_0, a0);
      a1 = fmaf(lp[4 * ii + 1], w_1, a1);
      a2 = fmaf(lp[4 * ii + 2], w_2, a2);
      a3 = fmaf(lp[4 * ii + 3], w_3, a3);
    }
    s_part[kh][r][lane] = (a0 + a1) + (a2 + a3);
  }
  __syncthreads();
  if (kh == 0)
    hs[r][lane] = fmaxf(s_part[0][r][lane] + s_part[1][r][lane] + b1[j], 0.f);
  __syncthreads();

  // W2 phase: row r, cols kh*128 + 2*lane(+1); float2 loads, 2 chains
  {
    const int c0 = kh * 128 + 2 * lane;
    const float* w2p = W2 + (size_t)(kt * 64) * D + c0;
    float f0 = 0.f, f1 = 0.f;
    #pragma unroll 16
    for (int k = 0; k < 64; ++k) {
      const float2 w = *reinterpret_cast<const float2*>(w2p + (size_t)k * D);
      const float hv = hs[r][k];
      f0 = fmaf(hv, w.x, f0);
      f1 = fmaf(hv, w.y, f1);
    }
    float2 o = make_float2(f0, f1);
    *reinterpret_cast<float2*>(&partial[(size_t)(kt * 64 + mt * 4 + r) * 256 + c0]) = o;
  }
}

// ---------------- K3: reduce partials + residual + LN + out tile ----------------
// grid 256 = 1 block/CU: ct = bid&3, bp = bid>>2; 512 threads.
__global__ __launch_bounds__(512, 1)
void k_tail(const float* __restrict__ last, const float* __restrict__ partial,
            const float* __restrict__ b2, const float* __restrict__ ln_g,
            const float* __restrict__ ln_b, const float* __restrict__ Wo,
            float* __restrict__ out) {
  const int ct = blockIdx.x & 3, bp = blockIdx.x >> 2;
  const int tid = threadIdx.x, lane = tid & 63, wid = tid >> 6;

  __shared__ float s_y[2][256];
  __shared__ float s_yn[256];
  __shared__ float s_op[8][128];
  __shared__ float red[8];

  // Phase A: partial reduce, 2-way split over kt
  {
    const int col = tid & 255, khh = tid >> 8;
    float acc = khh ? 0.f : (last[bp * 256 + col] + b2[col]);
    #pragma unroll
    for (int kt = khh * 8; kt < khh * 8 + 8; ++kt)
      acc += partial[(size_t)(kt * 64 + bp) * 256 + col];
    s_y[khh][col] = acc;
  }
  __syncthreads();

  // Phase B: layernorm over 256
  float y = 0.f;
  if (tid < 256) y = s_y[0][tid] + s_y[1][tid];
  float ssum = (tid < 256) ? y : 0.f, ssq = (tid < 256) ? y * y : 0.f;
  #pragma unroll
  for (int o = 32; o; o >>= 1) { ssum += __shfl_xor(ssum, o); ssq += __shfl_xor(ssq, o); }
  if (tid < 256 && lane == 0) { red[wid] = ssum; red[4 + wid] = ssq; }
  __syncthreads();
  ssum = red[0] + red[1] + red[2] + red[3];
  ssq  = red[4] + red[5] + red[6] + red[7];
  const float mu   = ssum / 256.f;
  const float var  = ssq / 256.f - mu * mu;
  const float rstd = rsqrtf(var + 1e-5f);
  if (tid < 256) s_yn[tid] = (y - mu) * rstd * ln_g[tid] + ln_b[tid];
  __syncthreads();

  // Phase C: out tile (128 cols), float2 Wo loads, 8-way K-split
  {
    const int l6 = tid & 63, kq = tid >> 6;
    const int c0 = ct * 128 + 2 * l6;
    float f0 = 0.f, f1 = 0.f;
    #pragma unroll 8
    for (int i = kq * 32; i < kq * 32 + 32; ++i) {
      const float2 w = *reinterpret_cast<const float2*>(&Wo[(size_t)i * DM + c0]);
      const float yv = s_yn[i];
      f0 = fmaf(yv, w.x, f0);
      f1 = fmaf(yv, w.y, f1);
    }
    s_op[kq][2 * l6] = f0; s_op[kq][2 * l6 + 1] = f1;
  }
  __syncthreads();
  if (tid < 128) {
    float a = 0.f;
    #pragma unroll
    for (int kq = 0; kq < 8; ++kq) a += s_op[kq][tid];
    out[(size_t)bp * DM + ct * 128 + tid] = a;
  }
}
}  // namespace

extern "C" void kernel_launch(void* const* d_in, const int* in_sizes, int n_in,
                              void* d_out, int out_size, void* d_ws, size_t ws_size,
                              hipStream_t stream) {
  const float* x    = (const float*)d_in[0];
  const float* t    = (const float*)d_in[1];
  const int*   mask = (const int*)  d_in[2];
  const float* emb  = (const float*)d_in[3];
  const float* Wq   = (const float*)d_in[4];
  const float* Wk   = (const float*)d_in[5];
  const float* Wv   = (const float*)d_in[6];
  const float* Wo   = (const float*)d_in[7];
  const float* lng  = (const float*)d_in[8];
  const float* lnb  = (const float*)d_in[9];
  const float* W1   = (const float*)d_in[10];
  const float* b1   = (const float*)d_in[11];
  const float* W2   = (const float*)d_in[12];
  const float* b2   = (const float*)d_in[13];
  float* out = (float*)d_out;

  float* ws      = (float*)d_ws;
  float* last    = ws;            // 64*256 floats
  float* partial = ws + 16384;    // 16*64*256 floats

  k_attn<<<512, 512, 0, stream>>>(x, t, mask, emb, Wq, Wk, Wv, last);
  k_ffn <<<256, 512, 0, stream>>>(last, W1, b1, W2, partial);
  k_tail<<<256, 512, 0, stream>>>(last, partial, b2, lng, lnb, Wo, out);
}

// Round 8
// 19.144 us; speedup vs baseline: 6.5565x; 1.2250x over previous
//
#include <hip/hip_runtime.h>
#include <math.h>

// B=8, PN=8 -> BP=64; PL=511 -> L=512; NV=2; H=8; DK=DV=32; D=256; DM=512; HID=1024.
namespace {
constexpr int L   = 512;
constexpr int D   = 256;
constexpr int DM  = 512;
constexpr int HID = 1024;
constexpr float INV_SQRT_DK = 0.17677669529663687f;  // 1/sqrt(32)

// thetas[j] = 1000^(-j/16), precomputed literals
__device__ __constant__ float THETA[16] = {
  1.0f,           0.64938163f,  0.42169650f,  0.27384196f,
  0.17782794f,    0.11547820f,  0.074989421f, 0.048696753f,
  0.031622777f,   0.020535250f, 0.013335214f, 0.0086596432f,
  0.0056234133f,  0.0036517412f,0.0023713737f,0.0015399265f };

// ---------------- K1: attention, one block per (bp, head) ---------------- (unchanged)
__global__ __launch_bounds__(512, 2)
void k_attn(const float* __restrict__ x, const float* __restrict__ t,
            const int* __restrict__ mask, const float* __restrict__ emb,
            const float* __restrict__ Wq, const float* __restrict__ Wk,
            const float* __restrict__ Wv, float* __restrict__ last) {
  const int bp = blockIdx.x & 63, h = blockIdx.x >> 6;
  const int tid = threadIdx.x, lane = tid & 63, wid = tid >> 6;

  __shared__ float wk0[32], wk1[32], wv0[32], wv1[32];
  __shared__ float red[24];

  if (tid < 32) {
    wk0[tid] = Wk[h * 32 + tid]; wk1[tid] = Wk[256 + h * 32 + tid];
    wv0[tid] = Wv[h * 32 + tid]; wv1[tid] = Wv[256 + h * 32 + tid];
  }

  const int   m0 = mask[bp * L];
  const float tl = t[bp * L + tid];
  const int   ml = mask[bp * L + tid];
  float xl0, xl1;
  if (tid == 0) { xl0 = emb[0]; xl1 = emb[1]; }
  else {
    float2 v = reinterpret_cast<const float2*>(x)[bp * (L - 1) + tid - 1];
    xl0 = v.x; xl1 = v.y;
  }

  float cj[16], sj[16];
  #pragma unroll
  for (int j = 0; j < 16; ++j) __sincosf(tl * THETA[j], &sj[j], &cj[j]);

  float qre = 0.f, qim = 0.f;
  if (lane < 16) {
    const float t0v = t[bp * L];
    const float e0 = emb[0], e1 = emb[1];
    const float re = e0 * Wq[h * 32 + 2 * lane]     + e1 * Wq[256 + h * 32 + 2 * lane];
    const float im = e0 * Wq[h * 32 + 2 * lane + 1] + e1 * Wq[256 + h * 32 + 2 * lane + 1];
    float s0, c0;
    __sincosf(t0v * THETA[lane], &s0, &c0);
    qre = (re * c0 - im * s0) * INV_SQRT_DK;
    qim = (re * s0 + im * c0) * INV_SQRT_DK;
  }
  __syncthreads();

  float sc = 0.f;
  #pragma unroll
  for (int j = 0; j < 16; ++j) {
    const int c = 2 * j;
    const float xr  = xl0 * wk0[c]     + xl1 * wk1[c];
    const float xi  = xl0 * wk0[c + 1] + xl1 * wk1[c + 1];
    const float kre = xr * cj[j] - xi * sj[j];
    const float kim = xr * sj[j] + xi * cj[j];
    sc += __shfl(qre, j) * kre + __shfl(qim, j) * kim;
  }

  const float e = (m0 == 0) ? 1.f : (ml ? __expf(sc) : 0.f);

  float se = e, s0a = e * xl0, s1a = e * xl1;
  #pragma unroll
  for (int o = 32; o; o >>= 1) {
    se  += __shfl_xor(se, o);
    s0a += __shfl_xor(s0a, o);
    s1a += __shfl_xor(s1a, o);
  }
  if (lane == 0) { red[wid] = se; red[8 + wid] = s0a; red[16 + wid] = s1a; }
  __syncthreads();
  se = 0.f; s0a = 0.f; s1a = 0.f;
  #pragma unroll
  for (int w = 0; w < 8; ++w) { se += red[w]; s0a += red[8 + w]; s1a += red[16 + w]; }

  if (tid < 32) last[bp * 256 + h * 32 + tid] = (s0a * wv0[tid] + s1a * wv1[tid]) / se;
}

// ---------------- K2: fused FFN1+FFN2, wave-cooperative (no redundant loads) ----------------
// grid 256 = 1 block/CU: kt = bid&15, mt = bid>>4. 512 threads = 8 waves.
// W1: wave w owns rows w*32..+32 (each W1 value feeds 4 row-accumulators).
// W2: wave w owns k-rows w*8..+8, float4 col loads. LDS combines partials.
__global__ __launch_bounds__(512, 1)
void k_ffn(const float* __restrict__ last, const float* __restrict__ W1,
           const float* __restrict__ b1, const float* __restrict__ W2,
           float* __restrict__ partial) {
  const int kt = blockIdx.x & 15, mt = blockIdx.x >> 4;
  const int tid = threadIdx.x, lane = tid & 63, w = tid >> 6;

  __shared__ float ls[4][256];        // last tile (4 bp rows)
  __shared__ float s_p1[8][4][64];    // W1 wave-partials
  __shared__ float hs[4][64];         // relu'd hidden tile
  __shared__ float s_p2[8][4][256];   // W2 wave-partials (32 KB)

  // stage `last` tile, coalesced
  #pragma unroll
  for (int q = 0; q < 2; ++q) {
    const int idx = tid + q * 512;
    ls[idx >> 8][idx & 255] = last[(mt * 4 + (idx >> 8)) * 256 + (idx & 255)];
  }
  __syncthreads();

  // ---- W1 phase: col j = kt*64+lane; wave w rows w*32..w*32+32 ----
  const int j = kt * 64 + lane;
  {
    const float* w1p = W1 + (size_t)(w * 32) * HID + j;
    float a0 = 0.f, a1 = 0.f, a2 = 0.f, a3 = 0.f;
    #pragma unroll
    for (int g = 0; g < 8; ++g) {
      const float4 l0 = *reinterpret_cast<const float4*>(&ls[0][w * 32 + g * 4]);
      const float4 l1 = *reinterpret_cast<const float4*>(&ls[1][w * 32 + g * 4]);
      const float4 l2 = *reinterpret_cast<const float4*>(&ls[2][w * 32 + g * 4]);
      const float4 l3 = *reinterpret_cast<const float4*>(&ls[3][w * 32 + g * 4]);
      const float w_0 = w1p[(g * 4 + 0) * HID];
      const float w_1 = w1p[(g * 4 + 1) * HID];
      const float w_2 = w1p[(g * 4 + 2) * HID];
      const float w_3 = w1p[(g * 4 + 3) * HID];
      a0 = fmaf(l0.x, w_0, a0); a0 = fmaf(l0.y, w_1, a0);
      a0 = fmaf(l0.z, w_2, a0); a0 = fmaf(l0.w, w_3, a0);
      a1 = fmaf(l1.x, w_0, a1); a1 = fmaf(l1.y, w_1, a1);
      a1 = fmaf(l1.z, w_2, a1); a1 = fmaf(l1.w, w_3, a1);
      a2 = fmaf(l2.x, w_0, a2); a2 = fmaf(l2.y, w_1, a2);
      a2 = fmaf(l2.z, w_2, a2); a2 = fmaf(l2.w, w_3, a2);
      a3 = fmaf(l3.x, w_0, a3); a3 = fmaf(l3.y, w_1, a3);
      a3 = fmaf(l3.z, w_2, a3); a3 = fmaf(l3.w, w_3, a3);
    }
    s_p1[w][0][lane] = a0; s_p1[w][1][lane] = a1;
    s_p1[w][2][lane] = a2; s_p1[w][3][lane] = a3;
  }
  __syncthreads();

  // ---- combine + bias + relu -> hs[4][64] ----
  if (tid < 256) {
    const int r = tid >> 6, k = tid & 63;
    float h = b1[kt * 64 + k];
    #pragma unroll
    for (int ww = 0; ww < 8; ++ww) h += s_p1[ww][r][k];
    hs[r][k] = fmaxf(h, 0.f);
  }
  __syncthreads();

  // ---- W2 phase: wave w k-rows w*8..+8; cols lane*4 (float4) ----
  {
    float hr[4][8];
    #pragma unroll
    for (int r = 0; r < 4; ++r) {
      *reinterpret_cast<float4*>(&hr[r][0]) = *reinterpret_cast<const float4*>(&hs[r][w * 8]);
      *reinterpret_cast<float4*>(&hr[r][4]) = *reinterpret_cast<const float4*>(&hs[r][w * 8 + 4]);
    }
    float4 c0 = {0,0,0,0}, c1 = {0,0,0,0}, c2 = {0,0,0,0}, c3 = {0,0,0,0};
    const float* w2p = W2 + (size_t)(kt * 64 + w * 8) * D + lane * 4;
    #pragma unroll
    for (int k = 0; k < 8; ++k) {
      const float4 wv = *reinterpret_cast<const float4*>(w2p + (size_t)k * D);
      c0.x = fmaf(hr[0][k], wv.x, c0.x); c0.y = fmaf(hr[0][k], wv.y, c0.y);
      c0.z = fmaf(hr[0][k], wv.z, c0.z); c0.w = fmaf(hr[0][k], wv.w, c0.w);
      c1.x = fmaf(hr[1][k], wv.x, c1.x); c1.y = fmaf(hr[1][k], wv.y, c1.y);
      c1.z = fmaf(hr[1][k], wv.z, c1.z); c1.w = fmaf(hr[1][k], wv.w, c1.w);
      c2.x = fmaf(hr[2][k], wv.x, c2.x); c2.y = fmaf(hr[2][k], wv.y, c2.y);
      c2.z = fmaf(hr[2][k], wv.z, c2.z); c2.w = fmaf(hr[2][k], wv.w, c2.w);
      c3.x = fmaf(hr[3][k], wv.x, c3.x); c3.y = fmaf(hr[3][k], wv.y, c3.y);
      c3.z = fmaf(hr[3][k], wv.z, c3.z); c3.w = fmaf(hr[3][k], wv.w, c3.w);
    }
    *reinterpret_cast<float4*>(&s_p2[w][0][lane * 4]) = c0;
    *reinterpret_cast<float4*>(&s_p2[w][1][lane * 4]) = c1;
    *reinterpret_cast<float4*>(&s_p2[w][2][lane * 4]) = c2;
    *reinterpret_cast<float4*>(&s_p2[w][3][lane * 4]) = c3;
  }
  __syncthreads();

  // ---- final combine over 8 wave-partials; float2 store ----
  {
    const int r = tid >> 7, c0i = (tid & 127) * 2;
    float v0 = 0.f, v1 = 0.f;
    #pragma unroll
    for (int ww = 0; ww < 8; ++ww) {
      v0 += s_p2[ww][r][c0i];
      v1 += s_p2[ww][r][c0i + 1];
    }
    *reinterpret_cast<float2*>(
        &partial[(size_t)(kt * 64 + mt * 4 + r) * 256 + c0i]) = make_float2(v0, v1);
  }
}

// ---------------- K3: reduce partials + residual + LN + out tile ---------------- (unchanged)
__global__ __launch_bounds__(512, 1)
void k_tail(const float* __restrict__ last, const float* __restrict__ partial,
            const float* __restrict__ b2, const float* __restrict__ ln_g,
            const float* __restrict__ ln_b, const float* __restrict__ Wo,
            float* __restrict__ out) {
  const int ct = blockIdx.x & 3, bp = blockIdx.x >> 2;
  const int tid = threadIdx.x, lane = tid & 63, wid = tid >> 6;

  __shared__ float s_y[2][256];
  __shared__ float s_yn[256];
  __shared__ float s_op[8][128];
  __shared__ float red[8];

  {
    const int col = tid & 255, khh = tid >> 8;
    float acc = khh ? 0.f : (last[bp * 256 + col] + b2[col]);
    #pragma unroll
    for (int kt = khh * 8; kt < khh * 8 + 8; ++kt)
      acc += partial[(size_t)(kt * 64 + bp) * 256 + col];
    s_y[khh][col] = acc;
  }
  __syncthreads();

  float y = 0.f;
  if (tid < 256) y = s_y[0][tid] + s_y[1][tid];
  float ssum = (tid < 256) ? y : 0.f, ssq = (tid < 256) ? y * y : 0.f;
  #pragma unroll
  for (int o = 32; o; o >>= 1) { ssum += __shfl_xor(ssum, o); ssq += __shfl_xor(ssq, o); }
  if (tid < 256 && lane == 0) { red[wid] = ssum; red[4 + wid] = ssq; }
  __syncthreads();
  ssum = red[0] + red[1] + red[2] + red[3];
  ssq  = red[4] + red[5] + red[6] + red[7];
  const float mu   = ssum / 256.f;
  const float var  = ssq / 256.f - mu * mu;
  const float rstd = rsqrtf(var + 1e-5f);
  if (tid < 256) s_yn[tid] = (y - mu) * rstd * ln_g[tid] + ln_b[tid];
  __syncthreads();

  {
    const int l6 = tid & 63, kq = tid >> 6;
    const int c0 = ct * 128 + 2 * l6;
    float f0 = 0.f, f1 = 0.f;
    #pragma unroll 8
    for (int i = kq * 32; i < kq * 32 + 32; ++i) {
      const float2 wv = *reinterpret_cast<const float2*>(&Wo[(size_t)i * DM + c0]);
      const float yv = s_yn[i];
      f0 = fmaf(yv, wv.x, f0);
      f1 = fmaf(yv, wv.y, f1);
    }
    s_op[kq][2 * l6] = f0; s_op[kq][2 * l6 + 1] = f1;
  }
  __syncthreads();
  if (tid < 128) {
    float a = 0.f;
    #pragma unroll
    for (int kq = 0; kq < 8; ++kq) a += s_op[kq][tid];
    out[(size_t)bp * DM + ct * 128 + tid] = a;
  }
}
}  // namespace

extern "C" void kernel_launch(void* const* d_in, const int* in_sizes, int n_in,
                              void* d_out, int out_size, void* d_ws, size_t ws_size,
                              hipStream_t stream) {
  const float* x    = (const float*)d_in[0];
  const float* t    = (const float*)d_in[1];
  const int*   mask = (const int*)  d_in[2];
  const float* emb  = (const float*)d_in[3];
  const float* Wq   = (const float*)d_in[4];
  const float* Wk   = (const float*)d_in[5];
  const float* Wv   = (const float*)d_in[6];
  const float* Wo   = (const float*)d_in[7];
  const float* lng  = (const float*)d_in[8];
  const float* lnb  = (const float*)d_in[9];
  const float* W1   = (const float*)d_in[10];
  const float* b1   = (const float*)d_in[11];
  const float* W2   = (const float*)d_in[12];
  const float* b2   = (const float*)d_in[13];
  float* out = (float*)d_out;

  float* ws      = (float*)d_ws;
  float* last    = ws;            // 64*256 floats
  float* partial = ws + 16384;    // 16*64*256 floats

  k_attn<<<512, 512, 0, stream>>>(x, t, mask, emb, Wq, Wk, Wv, last);
  k_ffn <<<256, 512, 0, stream>>>(last, W1, b1, W2, partial);
  k_tail<<<256, 512, 0, stream>>>(last, partial, b2, lng, lnb, Wo, out);
}